// Round 1
// baseline (5270.111 us; speedup 1.0000x reference)
//
#include <hip/hip_runtime.h>

#define TS 256
#define BB 256
#define ED 256
#define HD 512

typedef __bf16 bf16_t;
typedef bf16_t bf16x8 __attribute__((ext_vector_type(8)));
typedef float f32x16 __attribute__((ext_vector_type(16)));
typedef float f32x4_t __attribute__((ext_vector_type(4)));
typedef unsigned short u16x8 __attribute__((ext_vector_type(8)));

// workspace layout (bytes)
#define HB_BYTES (BB*HD*2)               // one h buffer (bf16 [256][512])
#define EBUF_OFF (2*HB_BYTES)            // bf16 embedding table [512][256]
#define FLAGS_OFF (EBUF_OFF + 512*ED*2)  // 256 int flags

// LDS layout (bytes)
#define L_AE   0        // A e-part  [32][512B]  (XOR-swizzled)
#define L_AH   16384    // A h-part  [32][1024B] (XOR-swizzled)
#define L_PB   49152    // partials  [4][32][65] f32 (bank = row+col, conflict-free)
#define L_ACT  82432    // activated gates [64][36] f32
#define L_OT   91648    // h f32 tile [32][20]
#define L_BIAS 94208    // 64 f32
#define L_TOT  94464    // 94.5 KB -> exactly 1 block/CU (co-residency guarantee)

__device__ __forceinline__ unsigned short f2bf(float f) {
  unsigned u = __builtin_bit_cast(unsigned, f);
  u += 0x7FFFu + ((u >> 16) & 1u);     // RNE
  return (unsigned short)(u >> 16);
}
__device__ __forceinline__ float sigm(float x) {
  return __builtin_amdgcn_rcpf(1.f + __expf(-x));
}
__device__ __forceinline__ float tanhf_(float x) {
  // stable: x->+inf => 1, x->-inf => -1 (no inf/inf)
  return 1.f - 2.f * __builtin_amdgcn_rcpf(1.f + __expf(2.f * x));
}

__global__ void emb2bf_kernel(const float* __restrict__ emb,
                              unsigned short* __restrict__ ebuf) {
  int i = blockIdx.x * 256 + threadIdx.x;   // 512*256 elements
  ebuf[i] = f2bf(emb[i]);
}

__global__ __launch_bounds__(256, 1) void lstm_kernel(
    const int* __restrict__ xs, const float* __restrict__ Wih,
    const float* __restrict__ Whh, const float* __restrict__ bih,
    const float* __restrict__ bhh, char* __restrict__ ws,
    float* __restrict__ out)
{
  __shared__ __align__(128) char lds[L_TOT];
  const int tid  = threadIdx.x;
  const int lane = tid & 63;
  const int wv   = tid >> 6;          // wave 0..3
  const int bg   = blockIdx.x & 7;    // batch group (rows bg*32..+32)
  const int gt   = blockIdx.x >> 3;   // gate tile (hidden units gt*16..+16, all 4 gates)

  char* hb = ws;                                  // [2][256][512] bf16
  const char* ebuf = ws + EBUF_OFF;
  int* flags = (int*)(ws + FLAGS_OFF);

  // ---- persistent weight fragments in VGPRs (bf16), K split across waves ----
  // wave wv: e-k in [64*wv, 64*wv+64), h-k in [128*wv, 128*wv+128)
  bf16x8 be[4][2], bhf[8][2];
  {
    const int kl = (lane >> 5) << 3;   // k sub-offset 0/8 per lane half
    #pragma unroll
    for (int nt = 0; nt < 2; ++nt) {
      const int col = nt*32 + (lane & 31);                 // local gate col 0..63
      const int gr  = (col >> 4)*HD + gt*16 + (col & 15);  // global gate row
      const float* wa = Wih + (size_t)gr * ED;
      const float* wb = Whh + (size_t)gr * HD;
      #pragma unroll
      for (int ks = 0; ks < 4; ++ks) {
        u16x8 tmp;
        #pragma unroll
        for (int j = 0; j < 8; ++j) tmp[j] = f2bf(wa[64*wv + 16*ks + kl + j]);
        be[ks][nt] = __builtin_bit_cast(bf16x8, tmp);
      }
      #pragma unroll
      for (int ks = 0; ks < 8; ++ks) {
        u16x8 tmp;
        #pragma unroll
        for (int j = 0; j < 8; ++j) tmp[j] = f2bf(wb[128*wv + 16*ks + kl + j]);
        bhf[ks][nt] = __builtin_bit_cast(bf16x8, tmp);
      }
    }
  }
  if (tid < 64) {
    const int gr = (tid >> 4)*HD + gt*16 + (tid & 15);
    *(float*)(lds + L_BIAS + tid*4) = bih[gr] + bhh[gr];
  }

  float cr0 = 0.f, cr1 = 0.f;              // c-state: (row ur, units uj, uj+8)
  const int ur = tid & 31, uj = tid >> 5;

  // ---- stage Ae for t=0 ----
  {
    int4 aev[4];
    #pragma unroll
    for (int i = 0; i < 4; ++i) {
      const int lin = (i*256 + tid) * 16;
      const int row = lin >> 9, inner = lin & 511;
      const int xv = xs[bg*32 + row];
      aev[i] = *(const int4*)(ebuf + xv*512 + inner);
    }
    #pragma unroll
    for (int i = 0; i < 4; ++i) {
      const int lin = (i*256 + tid) * 16;
      const int row = lin >> 9, inner = lin & 511;
      *(int4*)(lds + L_AE + row*512 + (inner ^ ((row & 7) << 4))) = aev[i];
    }
  }
  __syncthreads();

  for (int t = 0; t < TS; ++t) {
    const int p = t & 1;   // read h_{t-1} from hb[p], write h_t to hb[p^1]

    // ---- e-part MFMA (independent of h -> before the group barrier) ----
    f32x16 acc0 = {}, acc1 = {};
    #pragma unroll
    for (int ks = 0; ks < 4; ++ks) {
      const int row = lane & 31;
      const int koff = (64*wv + 16*ks)*2 + ((lane >> 5) << 4);
      bf16x8 a = *(const bf16x8*)(lds + L_AE + row*512 + (koff ^ ((row & 7) << 4)));
      acc0 = __builtin_amdgcn_mfma_f32_32x32x16_bf16(a, be[ks][0], acc0, 0, 0, 0);
      acc1 = __builtin_amdgcn_mfma_f32_32x32x16_bf16(a, be[ks][1], acc1, 0, 0, 0);
    }

    // ---- group barrier: wait for all 32 blocks of this batch group ----
    {
      const int poll = (lane < 32);
      int* fp = flags + bg*32 + (lane & 31);
      int it = 0;
      for (;;) {
        int v = poll ? __hip_atomic_load(fp, __ATOMIC_RELAXED, __HIP_MEMORY_SCOPE_AGENT) : t;
        if (__all(v >= t)) break;
        if (++it > (1 << 18)) break;   // safety valve (never hit in normal operation)
        __builtin_amdgcn_s_sleep(1);
      }
      __builtin_amdgcn_fence(__ATOMIC_ACQUIRE, "agent");
    }

    // ---- stage Ah (h_{t-1}) ----
    int4 ahv[8];
    #pragma unroll
    for (int i = 0; i < 8; ++i) {
      const int lin = (i*256 + tid) * 16;
      const int row = lin >> 10, inner = lin & 1023;
      ahv[i] = *(const int4*)(hb + p*HB_BYTES + (bg*32 + row)*1024 + inner);
    }
    #pragma unroll
    for (int i = 0; i < 8; ++i) {
      const int lin = (i*256 + tid) * 16;
      const int row = lin >> 10, inner = lin & 1023;
      *(int4*)(lds + L_AH + row*1024 + (inner ^ ((row & 7) << 4))) = ahv[i];
    }
    __syncthreads();   // B1

    // ---- h-part MFMA ----
    #pragma unroll
    for (int ks = 0; ks < 8; ++ks) {
      const int row = lane & 31;
      const int koff = (128*wv + 16*ks)*2 + ((lane >> 5) << 4);
      bf16x8 a = *(const bf16x8*)(lds + L_AH + row*1024 + (koff ^ ((row & 7) << 4)));
      acc0 = __builtin_amdgcn_mfma_f32_32x32x16_bf16(a, bhf[ks][0], acc0, 0, 0, 0);
      acc1 = __builtin_amdgcn_mfma_f32_32x32x16_bf16(a, bhf[ks][1], acc1, 0, 0, 0);
    }

    // ---- write K-split partials (conflict-free: bank = row + col) ----
    #pragma unroll
    for (int r = 0; r < 16; ++r) {
      const int row = (r & 3) + 8*(r >> 2) + 4*(lane >> 5);
      char* base = lds + L_PB + wv*8320 + row*260;
      *(float*)(base + (lane & 31)*4)        = acc0[r];
      *(float*)(base + (32 + (lane & 31))*4) = acc1[r];
    }
    __syncthreads();   // B2

    // ---- issue next-step embedding gather (overlaps activation) ----
    int4 aev[4];
    if (t < TS-1) {
      #pragma unroll
      for (int i = 0; i < 4; ++i) {
        const int lin = (i*256 + tid) * 16;
        const int row = lin >> 9, inner = lin & 511;
        const int xv = xs[(t+1)*BB + bg*32 + row];
        aev[i] = *(const int4*)(ebuf + xv*512 + inner);
      }
    }

    // ---- reduce partials + activations (wave wv handles gate wv: uniform) ----
    {
      const int c  = wv*16 + (lane & 15);
      const int rg = lane >> 4;
      const float bv = *(const float*)(lds + L_BIAS + c*4);
      float g[8];
      #pragma unroll
      for (int j = 0; j < 8; ++j) {
        const int row = rg*8 + j;
        float s = bv;
        #pragma unroll
        for (int pp = 0; pp < 4; ++pp)
          s += *(const float*)(lds + L_PB + pp*8320 + row*260 + c*4);
        g[j] = (wv == 2) ? tanhf_(s) : sigm(s);
      }
      f32x4_t v0 = {g[0], g[1], g[2], g[3]};
      f32x4_t v1 = {g[4], g[5], g[6], g[7]};
      *(f32x4_t*)(lds + L_ACT + c*144 + rg*32)      = v0;
      *(f32x4_t*)(lds + L_ACT + c*144 + rg*32 + 16) = v1;
    }

    if (t < TS-1) {
      #pragma unroll
      for (int i = 0; i < 4; ++i) {
        const int lin = (i*256 + tid) * 16;
        const int row = lin >> 9, inner = lin & 511;
        *(int4*)(lds + L_AE + row*512 + (inner ^ ((row & 7) << 4))) = aev[i];
      }
    }
    __syncthreads();   // B3

    // ---- c/h update (2 hidden units per thread, c in registers) ----
    {
      const float iv0 = *(const float*)(lds + L_ACT + ( 0 + uj)*144 + ur*4);
      const float fv0 = *(const float*)(lds + L_ACT + (16 + uj)*144 + ur*4);
      const float gv0 = *(const float*)(lds + L_ACT + (32 + uj)*144 + ur*4);
      const float ov0 = *(const float*)(lds + L_ACT + (48 + uj)*144 + ur*4);
      const float iv1 = *(const float*)(lds + L_ACT + ( 8 + uj)*144 + ur*4);
      const float fv1 = *(const float*)(lds + L_ACT + (24 + uj)*144 + ur*4);
      const float gv1 = *(const float*)(lds + L_ACT + (40 + uj)*144 + ur*4);
      const float ov1 = *(const float*)(lds + L_ACT + (56 + uj)*144 + ur*4);
      cr0 = fv0*cr0 + iv0*gv0;
      cr1 = fv1*cr1 + iv1*gv1;
      const float h0 = ov0 * tanhf_(cr0);
      const float h1 = ov1 * tanhf_(cr1);
      *(float*)(lds + L_OT + ur*80 + uj*4)     = h0;
      *(float*)(lds + L_OT + ur*80 + (uj+8)*4) = h1;
      if (t == TS-1) {
        float* cb = out + (size_t)TS*BB*HD + (size_t)BB*HD;
        cb[(size_t)(bg*32 + ur)*HD + gt*16 + uj]     = cr0;
        cb[(size_t)(bg*32 + ur)*HD + gt*16 + uj + 8] = cr1;
      }
    }
    __syncthreads();   // B4

    // ---- stores: wave0 -> hb (bf16), wave1 -> outs (f32) ----
    if (wv == 0) {
      const int row = lane >> 1, hf = lane & 1;
      f32x4_t a_ = *(const f32x4_t*)(lds + L_OT + row*80 + hf*32);
      f32x4_t b_ = *(const f32x4_t*)(lds + L_OT + row*80 + hf*32 + 16);
      u16x8 hv;
      #pragma unroll
      for (int j = 0; j < 4; ++j) { hv[j] = f2bf(a_[j]); hv[4+j] = f2bf(b_[j]); }
      *(u16x8*)(hb + (p^1)*HB_BYTES + (bg*32 + row)*1024 + gt*32 + hf*16) = hv;
    } else if (wv == 1) {
      const int row = lane >> 1, hf = lane & 1;
      f32x4_t a_ = *(const f32x4_t*)(lds + L_OT + row*80 + hf*32);
      f32x4_t b_ = *(const f32x4_t*)(lds + L_OT + row*80 + hf*32 + 16);
      float* ob = out + ((size_t)t*BB + bg*32 + row)*HD + gt*16 + hf*8;
      *(f32x4_t*)ob       = a_;
      *(f32x4_t*)(ob + 4) = b_;
      if (t == TS-1) {
        float* ho = out + (size_t)TS*BB*HD + (size_t)(bg*32 + row)*HD + gt*16 + hf*8;
        *(f32x4_t*)ho       = a_;
        *(f32x4_t*)(ho + 4) = b_;
      }
    }
    // release: orders wave0's hb stores before the flag becomes visible
    if (tid == 0)
      __hip_atomic_store(flags + bg*32 + gt, t + 1, __ATOMIC_RELEASE, __HIP_MEMORY_SCOPE_AGENT);
  }
}

extern "C" void kernel_launch(void* const* d_in, const int* in_sizes, int n_in,
                              void* d_out, int out_size, void* d_ws, size_t ws_size,
                              hipStream_t stream) {
  (void)in_sizes; (void)n_in; (void)out_size; (void)ws_size;
  const int*   xs  = (const int*)d_in[0];
  const float* emb = (const float*)d_in[1];
  const float* Wih = (const float*)d_in[2];
  const float* Whh = (const float*)d_in[3];
  const float* bih = (const float*)d_in[4];
  const float* bhh = (const float*)d_in[5];
  char* ws = (char*)d_ws;

  // deterministic per-call init: h_{-1} = 0, flags = 0
  hipMemsetAsync(ws, 0, HB_BYTES, stream);
  hipMemsetAsync(ws + FLAGS_OFF, 0, 256*4, stream);
  emb2bf_kernel<<<512, 256, 0, stream>>>(emb, (unsigned short*)(ws + EBUF_OFF));
  lstm_kernel<<<256, 256, 0, stream>>>(xs, Wih, Whh, bih, bhh, ws, (float*)d_out);
}

// Round 3
// 1002.476 us; speedup vs baseline: 5.2571x; 5.2571x over previous
//
#include <hip/hip_runtime.h>

#define TS 256
#define BB 256
#define ED 256
#define HD 512

typedef __bf16 bf16_t;
typedef bf16_t bf16x8 __attribute__((ext_vector_type(8)));
typedef float f32x16 __attribute__((ext_vector_type(16)));
typedef float f32x4_t __attribute__((ext_vector_type(4)));
typedef unsigned short u16x8 __attribute__((ext_vector_type(8)));
typedef int i32x4 __attribute__((ext_vector_type(4)));

// workspace layout (bytes)
#define HB_BYTES (BB*HD*2)               // one h buffer (bf16 [256][512])
#define EBUF_OFF (2*HB_BYTES)            // bf16 embedding table [512][256]
#define FLAGS_OFF (EBUF_OFF + 512*ED*2)  // 256 int flags

// LDS layout (bytes)
#define L_AE   0        // A e-part  [32][512B]  (XOR-swizzled)
#define L_AH   16384    // A h-part  [32][1024B] (XOR-swizzled)
#define L_PB   49152    // partials  [4][32][65] f32 (bank = row+col, conflict-free)
#define L_ACT  82432    // activated gates [64][36] f32
#define L_OT   91648    // h f32 tile [32][20]
#define L_BIAS 94208    // 64 f32
#define L_TOT  94464    // 94.5 KB -> exactly 1 block/CU (co-residency guarantee)

__device__ __forceinline__ unsigned short f2bf(float f) {
  unsigned u = __builtin_bit_cast(unsigned, f);
  u += 0x7FFFu + ((u >> 16) & 1u);     // RNE
  return (unsigned short)(u >> 16);
}
__device__ __forceinline__ float sigm(float x) {
  return __builtin_amdgcn_rcpf(1.f + __expf(-x));
}
__device__ __forceinline__ float tanhf_(float x) {
  return 1.f - 2.f * __builtin_amdgcn_rcpf(1.f + __expf(2.f * x));
}

// ---- device-scope (sc1) memory ops: coherent across XCDs, NO wbl2/inv ----
__device__ __forceinline__ void store_sc1_x4(void* p, i32x4 v) {
  asm volatile("global_store_dwordx4 %0, %1, off sc1" :: "v"(p), "v"(v) : "memory");
}
__device__ __forceinline__ i32x4 load_sc1_x4_issue(const void* p) {
  i32x4 r;
  asm volatile("global_load_dwordx4 %0, %1, off sc1" : "=v"(r) : "v"(p) : "memory");
  return r;
}
__device__ __forceinline__ int load_sc1_dw(const void* p) {
  int r;
  asm volatile("global_load_dword %0, %1, off sc1\n\ts_waitcnt vmcnt(0)"
               : "=v"(r) : "v"(p) : "memory");
  return r;
}
__device__ __forceinline__ void fence_vm() {
  asm volatile("s_waitcnt vmcnt(0)" ::: "memory");
}

__global__ void emb2bf_kernel(const float* __restrict__ emb,
                              unsigned short* __restrict__ ebuf) {
  int i = blockIdx.x * 256 + threadIdx.x;   // 512*256 elements
  ebuf[i] = f2bf(emb[i]);
}

__global__ __launch_bounds__(256, 1) void lstm_kernel(
    const int* __restrict__ xs, const float* __restrict__ Wih,
    const float* __restrict__ Whh, const float* __restrict__ bih,
    const float* __restrict__ bhh, char* __restrict__ ws,
    float* __restrict__ out)
{
  __shared__ __align__(128) char lds[L_TOT];
  const int tid  = threadIdx.x;
  const int lane = tid & 63;
  const int wv   = tid >> 6;          // wave 0..3
  const int bg   = blockIdx.x & 7;    // batch group (rows bg*32..+32)
  const int gt   = blockIdx.x >> 3;   // gate tile (hidden units gt*16..+16, all 4 gates)

  char* hb = ws;                                  // [2][256][512] bf16
  const char* ebuf = ws + EBUF_OFF;
  int* flags = (int*)(ws + FLAGS_OFF);

  // ---- persistent weight fragments in VGPRs (bf16), K split across waves ----
  bf16x8 be[4][2], bhf[8][2];
  {
    const int kl = (lane >> 5) << 3;
    #pragma unroll
    for (int nt = 0; nt < 2; ++nt) {
      const int col = nt*32 + (lane & 31);
      const int gr  = (col >> 4)*HD + gt*16 + (col & 15);
      const float* wa = Wih + (size_t)gr * ED;
      const float* wb = Whh + (size_t)gr * HD;
      #pragma unroll
      for (int ks = 0; ks < 4; ++ks) {
        u16x8 tmp;
        #pragma unroll
        for (int j = 0; j < 8; ++j) tmp[j] = f2bf(wa[64*wv + 16*ks + kl + j]);
        be[ks][nt] = __builtin_bit_cast(bf16x8, tmp);
      }
      #pragma unroll
      for (int ks = 0; ks < 8; ++ks) {
        u16x8 tmp;
        #pragma unroll
        for (int j = 0; j < 8; ++j) tmp[j] = f2bf(wb[128*wv + 16*ks + kl + j]);
        bhf[ks][nt] = __builtin_bit_cast(bf16x8, tmp);
      }
    }
  }
  if (tid < 64) {
    const int gr = (tid >> 4)*HD + gt*16 + (tid & 15);
    *(float*)(lds + L_BIAS + tid*4) = bih[gr] + bhh[gr];
  }

  float cr0 = 0.f, cr1 = 0.f;
  const int ur = tid & 31, uj = tid >> 5;

  // ---- stage Ae for t=0 ----
  {
    i32x4 aev[4];
    #pragma unroll
    for (int i = 0; i < 4; ++i) {
      const int lin = (i*256 + tid) * 16;
      const int row = lin >> 9, inner = lin & 511;
      const int xv = xs[bg*32 + row];
      aev[i] = *(const i32x4*)(ebuf + xv*512 + inner);
    }
    #pragma unroll
    for (int i = 0; i < 4; ++i) {
      const int lin = (i*256 + tid) * 16;
      const int row = lin >> 9, inner = lin & 511;
      *(i32x4*)(lds + L_AE + row*512 + (inner ^ ((row & 7) << 4))) = aev[i];
    }
  }
  __syncthreads();

  for (int t = 0; t < TS; ++t) {
    const int p = t & 1;   // read h_{t-1} from hb[p], write h_t to hb[p^1]

    // ---- e-part MFMA (independent of h -> before the group barrier) ----
    f32x16 acc0 = {}, acc1 = {};
    #pragma unroll
    for (int ks = 0; ks < 4; ++ks) {
      const int row = lane & 31;
      const int koff = (64*wv + 16*ks)*2 + ((lane >> 5) << 4);
      bf16x8 a = *(const bf16x8*)(lds + L_AE + row*512 + (koff ^ ((row & 7) << 4)));
      acc0 = __builtin_amdgcn_mfma_f32_32x32x16_bf16(a, be[ks][0], acc0, 0, 0, 0);
      acc1 = __builtin_amdgcn_mfma_f32_32x32x16_bf16(a, be[ks][1], acc1, 0, 0, 0);
    }

    // ---- group barrier: wait for all 32 blocks of this batch group ----
    {
      const int* fp = flags + bg*32 + (lane & 31);
      int it = 0;
      for (;;) {
        int v = load_sc1_dw(fp);
        if (__all(v >= t)) break;
        if (++it > (1 << 18)) break;   // safety valve (never hit normally)
        __builtin_amdgcn_s_sleep(1);
      }
    }

    // ---- stage Ah (h_{t-1}): sc1 loads, fresh at device coherence point ----
    i32x4 ahv[8];
    #pragma unroll
    for (int i = 0; i < 8; ++i) {
      const int lin = (i*256 + tid) * 16;
      const int row = lin >> 10, inner = lin & 1023;
      ahv[i] = load_sc1_x4_issue(hb + p*HB_BYTES + (bg*32 + row)*1024 + inner);
    }
    fence_vm();
    __builtin_amdgcn_sched_barrier(0);
    #pragma unroll
    for (int i = 0; i < 8; ++i) {
      const int lin = (i*256 + tid) * 16;
      const int row = lin >> 10, inner = lin & 1023;
      *(i32x4*)(lds + L_AH + row*1024 + (inner ^ ((row & 7) << 4))) = ahv[i];
    }
    __syncthreads();   // B1

    // ---- h-part MFMA ----
    #pragma unroll
    for (int ks = 0; ks < 8; ++ks) {
      const int row = lane & 31;
      const int koff = (128*wv + 16*ks)*2 + ((lane >> 5) << 4);
      bf16x8 a = *(const bf16x8*)(lds + L_AH + row*1024 + (koff ^ ((row & 7) << 4)));
      acc0 = __builtin_amdgcn_mfma_f32_32x32x16_bf16(a, bhf[ks][0], acc0, 0, 0, 0);
      acc1 = __builtin_amdgcn_mfma_f32_32x32x16_bf16(a, bhf[ks][1], acc1, 0, 0, 0);
    }

    // ---- write K-split partials (bank = row + col, conflict-free) ----
    #pragma unroll
    for (int r = 0; r < 16; ++r) {
      const int row = (r & 3) + 8*(r >> 2) + 4*(lane >> 5);
      char* base = lds + L_PB + wv*8320 + row*260;
      *(float*)(base + (lane & 31)*4)        = acc0[r];
      *(float*)(base + (32 + (lane & 31))*4) = acc1[r];
    }
    __syncthreads();   // B2

    // ---- issue next-step embedding gather (overlaps activation) ----
    i32x4 aev[4];
    if (t < TS-1) {
      #pragma unroll
      for (int i = 0; i < 4; ++i) {
        const int lin = (i*256 + tid) * 16;
        const int row = lin >> 9, inner = lin & 511;
        const int xv = xs[(t+1)*BB + bg*32 + row];
        aev[i] = *(const i32x4*)(ebuf + xv*512 + inner);
      }
    }

    // ---- reduce partials + activations (wave wv handles gate wv) ----
    {
      const int c  = wv*16 + (lane & 15);
      const int rg = lane >> 4;
      const float bv = *(const float*)(lds + L_BIAS + c*4);
      float g[8];
      #pragma unroll
      for (int j = 0; j < 8; ++j) {
        const int row = rg*8 + j;
        float s = bv;
        #pragma unroll
        for (int pp = 0; pp < 4; ++pp)
          s += *(const float*)(lds + L_PB + pp*8320 + row*260 + c*4);
        g[j] = (wv == 2) ? tanhf_(s) : sigm(s);
      }
      f32x4_t v0 = {g[0], g[1], g[2], g[3]};
      f32x4_t v1 = {g[4], g[5], g[6], g[7]};
      *(f32x4_t*)(lds + L_ACT + c*144 + rg*32)      = v0;
      *(f32x4_t*)(lds + L_ACT + c*144 + rg*32 + 16) = v1;
    }

    if (t < TS-1) {
      #pragma unroll
      for (int i = 0; i < 4; ++i) {
        const int lin = (i*256 + tid) * 16;
        const int row = lin >> 9, inner = lin & 511;
        *(i32x4*)(lds + L_AE + row*512 + (inner ^ ((row & 7) << 4))) = aev[i];
      }
    }
    __syncthreads();   // B3

    // ---- c/h update ----
    {
      const float iv0 = *(const float*)(lds + L_ACT + ( 0 + uj)*144 + ur*4);
      const float fv0 = *(const float*)(lds + L_ACT + (16 + uj)*144 + ur*4);
      const float gv0 = *(const float*)(lds + L_ACT + (32 + uj)*144 + ur*4);
      const float ov0 = *(const float*)(lds + L_ACT + (48 + uj)*144 + ur*4);
      const float iv1 = *(const float*)(lds + L_ACT + ( 8 + uj)*144 + ur*4);
      const float fv1 = *(const float*)(lds + L_ACT + (24 + uj)*144 + ur*4);
      const float gv1 = *(const float*)(lds + L_ACT + (40 + uj)*144 + ur*4);
      const float ov1 = *(const float*)(lds + L_ACT + (56 + uj)*144 + ur*4);
      cr0 = fv0*cr0 + iv0*gv0;
      cr1 = fv1*cr1 + iv1*gv1;
      const float h0 = ov0 * tanhf_(cr0);
      const float h1 = ov1 * tanhf_(cr1);
      *(float*)(lds + L_OT + ur*80 + uj*4)     = h0;
      *(float*)(lds + L_OT + ur*80 + (uj+8)*4) = h1;
      if (t == TS-1) {
        float* cb = out + (size_t)TS*BB*HD + (size_t)BB*HD;
        cb[(size_t)(bg*32 + ur)*HD + gt*16 + uj]     = cr0;
        cb[(size_t)(bg*32 + ur)*HD + gt*16 + uj + 8] = cr1;
      }
    }
    __syncthreads();   // B4

    // ---- stores: wave0 -> hb (sc1 write-through), wave1 -> outs ----
    if (wv == 0) {
      const int row = lane >> 1, hf = lane & 1;
      f32x4_t a_ = *(const f32x4_t*)(lds + L_OT + row*80 + hf*32);
      f32x4_t b_ = *(const f32x4_t*)(lds + L_OT + row*80 + hf*32 + 16);
      u16x8 hv;
      #pragma unroll
      for (int j = 0; j < 4; ++j) { hv[j] = f2bf(a_[j]); hv[4+j] = f2bf(b_[j]); }
      store_sc1_x4(hb + (p^1)*HB_BYTES + (bg*32 + row)*1024 + gt*32 + hf*16,
                   __builtin_bit_cast(i32x4, hv));
    } else if (wv == 1) {
      const int row = lane >> 1, hf = lane & 1;
      f32x4_t a_ = *(const f32x4_t*)(lds + L_OT + row*80 + hf*32);
      f32x4_t b_ = *(const f32x4_t*)(lds + L_OT + row*80 + hf*32 + 16);
      float* ob = out + ((size_t)t*BB + bg*32 + row)*HD + gt*16 + hf*8;
      *(f32x4_t*)ob       = a_;
      *(f32x4_t*)(ob + 4) = b_;
      if (t == TS-1) {
        float* ho = out + (size_t)TS*BB*HD + (size_t)(bg*32 + row)*HD + gt*16 + hf*8;
        *(f32x4_t*)ho       = a_;
        *(f32x4_t*)(ho + 4) = b_;
      }
    }
    // release: drain wave0's sc1 data stores (ack at coherence point), THEN flag
    if (tid == 0) {
      int fv = t + 1;
      void* fp = flags + bg*32 + gt;
      asm volatile("s_waitcnt vmcnt(0)\n\tglobal_store_dword %0, %1, off sc1"
                   :: "v"(fp), "v"(fv) : "memory");
    }
  }
}

extern "C" void kernel_launch(void* const* d_in, const int* in_sizes, int n_in,
                              void* d_out, int out_size, void* d_ws, size_t ws_size,
                              hipStream_t stream) {
  (void)in_sizes; (void)n_in; (void)out_size; (void)ws_size;
  const int*   xs  = (const int*)d_in[0];
  const float* emb = (const float*)d_in[1];
  const float* Wih = (const float*)d_in[2];
  const float* Whh = (const float*)d_in[3];
  const float* bih = (const float*)d_in[4];
  const float* bhh = (const float*)d_in[5];
  char* ws = (char*)d_ws;

  (void)hipMemsetAsync(ws, 0, HB_BYTES, stream);
  (void)hipMemsetAsync(ws + FLAGS_OFF, 0, 256*4, stream);
  emb2bf_kernel<<<512, 256, 0, stream>>>(emb, (unsigned short*)(ws + EBUF_OFF));
  lstm_kernel<<<256, 256, 0, stream>>>(xs, Wih, Whh, bih, bhh, ws, (float*)d_out);
}